// Round 9
// baseline (176.013 us; speedup 1.0000x reference)
//
#include <hip/hip_runtime.h>

// Pipeline decomposition (per-phase rocprof attribution), attG eliminated.
//  bs=64, nq=64, E=256, Hn=8, dh=32, L=4, P=16, BEV=2, Pb=32
//  qb=128 collapses to 64. OFF col (h,f,c)=h*256+2f+c; rp level=f&3;
//  image level=f>>5; attn key=f; output pairs (2q,2q+1) -> rows pj/pj+32.
//
// ws: [0,2M) Qb bf16 4096x256 | [2M,4M) Khb bf16 4096x256
//     [4M,5M) Wtb bf16 2048x256 | [5M,9M) VTg bf16 [bh][32][128]
//     [9M,25.78M) OFFb bf16 4096x2048

typedef short  s16x8 __attribute__((ext_vector_type(8)));
typedef short  s16x4 __attribute__((ext_vector_type(4)));
typedef float  f32x4 __attribute__((ext_vector_type(4)));

__device__ __forceinline__ unsigned short f2bf(float f) {
    union { float f; unsigned u; } v; v.f = f;
    unsigned r = v.u + 0x7FFFu + ((v.u >> 16) & 1u);   // RNE
    return (unsigned short)(r >> 16);
}
__device__ __forceinline__ float bf2f(unsigned short u) {
    return __uint_as_float(((unsigned)u) << 16);
}

// ---------------------------------------------------------------------------
// K1 prep: [0,512) W transpose; [512,1536) query->Qb; [1536,2560) key->Khb;
//          [2560,3072) VTg build
// ---------------------------------------------------------------------------
__global__ __launch_bounds__(256) void prep(
    const float* __restrict__ W, const float* __restrict__ query,
    const float* __restrict__ key_hist, const float* __restrict__ value_hist,
    short* __restrict__ Wtb, short* __restrict__ Qb, short* __restrict__ Khb,
    short* __restrict__ VTg)
{
    __shared__ float s[32][33];
    const int bx = blockIdx.x, t = threadIdx.x;
    if (bx < 512) {
        const int n0 = (bx & 63) * 32, k0 = (bx >> 6) * 32;
        const int c = t & 31, r0 = t >> 5;
        #pragma unroll
        for (int p = 0; p < 4; ++p) {
            const int r = r0 + p * 8;
            s[r][c] = W[(size_t)(k0 + r) * 2048 + n0 + c];
        }
        __syncthreads();
        #pragma unroll
        for (int p = 0; p < 4; ++p) {
            const int r = r0 + p * 8;
            Wtb[(size_t)(n0 + r) * 256 + k0 + c] = (short)f2bf(s[c][r]);
        }
    } else if (bx < 2560) {
        const int j = bx - 512;
        const bool isK = j >= 1024;
        const float* src = isK ? key_hist : query;
        short* dst = isK ? Khb : Qb;
        const int i4 = ((j & 1023) * 256 + t) * 4;
        const float4 v = *(const float4*)(src + i4);
        s16x4 o;
        o.x = (short)f2bf(v.x); o.y = (short)f2bf(v.y);
        o.z = (short)f2bf(v.z); o.w = (short)f2bf(v.w);
        *(s16x4*)(dst + i4) = o;
    } else {
        const int bh = bx - 2560;            // 0..511
        const int b = bh >> 3, h = bh & 7;
        #pragma unroll
        for (int pass = 0; pass < 4; ++pass) {
            const int idx = t + 256 * pass;  // 0..1023
            const int p = idx >> 3;          // 0..127
            const int dg = idx & 7;          // 0..7
            const float* src = (p < 64) ? query : value_hist;
            const float4 v = *(const float4*)(src +
                (size_t)(b * 64 + (p & 63)) * 256 + h * 32 + dg * 4);
            short* o = VTg + ((size_t)bh * 32 + dg * 4) * 128 + p;
            o[0 * 128] = (short)f2bf(v.x);
            o[1 * 128] = (short)f2bf(v.y);
            o[2 * 128] = (short)f2bf(v.z);
            o[3 * 128] = (short)f2bf(v.w);
        }
    }
}

// ---------------------------------------------------------------------------
// K2 gemm: OFFb[4096][2048] = bf16( Qb @ Wtb^T + bias ). 128x128 tile,
// 4 waves 2x2, 4x4 MFMA 16x16x32; LDS epilogue for coalesced stores.
// ---------------------------------------------------------------------------
__global__ __launch_bounds__(256) void gemm_k(
    const short* __restrict__ Ab, const short* __restrict__ Wt,
    const float* __restrict__ bias, short* __restrict__ OFFb)
{
    __shared__ __align__(16) short smem[128 * 136];
    short (*Asl)[40] = (short (*)[40])smem;
    short (*Bsl)[40] = (short (*)[40])(smem + 128 * 40);
    short (*Cst)[136] = (short (*)[136])smem;

    const int n0 = blockIdx.x * 128, m0 = blockIdx.y * 128;
    const int t = threadIdx.x, lane = t & 63, wave = t >> 6;
    const int wm0 = (wave >> 1) * 64, wn0 = (wave & 1) * 64;
    const int r = lane & 15, q = lane >> 4;

    f32x4 acc[4][4] = {};
    for (int kc = 0; kc < 256; kc += 32) {
        #pragma unroll
        for (int ss = 0; ss < 2; ++ss) {
            const int seg = t + ss * 256;
            const int row = seg >> 2, off8 = (seg & 3) * 8;
            *(s16x8*)&Asl[row][off8] =
                *(const s16x8*)(Ab + (size_t)(m0 + row) * 256 + kc + off8);
            *(s16x8*)&Bsl[row][off8] =
                *(const s16x8*)(Wt + (size_t)(n0 + row) * 256 + kc + off8);
        }
        __syncthreads();
        s16x8 af[4], bf[4];
        #pragma unroll
        for (int i = 0; i < 4; ++i) {
            af[i] = *(const s16x8*)&Asl[wm0 + i * 16 + r][q * 8];
            bf[i] = *(const s16x8*)&Bsl[wn0 + i * 16 + r][q * 8];
        }
        #pragma unroll
        for (int i = 0; i < 4; ++i)
            #pragma unroll
            for (int j = 0; j < 4; ++j)
                acc[i][j] = __builtin_amdgcn_mfma_f32_16x16x32_bf16(
                    af[i], bf[j], acc[i][j], 0, 0, 0);
        __syncthreads();
    }
    #pragma unroll
    for (int j = 0; j < 4; ++j) {
        const float bb = bias[n0 + wn0 + j * 16 + r];
        #pragma unroll
        for (int i = 0; i < 4; ++i)
            #pragma unroll
            for (int rg = 0; rg < 4; ++rg)
                Cst[wm0 + i * 16 + q * 4 + rg][wn0 + j * 16 + r] =
                    (short)f2bf(acc[i][j][rg] + bb);
    }
    __syncthreads();
    {
        const int row = t >> 1, half = t & 1;
        short* gdst = OFFb + (size_t)(m0 + row) * 2048 + n0 + half * 64;
        const short* lsrc = &Cst[row][half * 64];
        #pragma unroll
        for (int u = 0; u < 8; ++u)
            *(s16x8*)(gdst + u * 8) = *(const s16x8*)(lsrc + u * 8);
    }
}

// ---------------------------------------------------------------------------
// K3 scatter_av (+in-kernel logits): grid (8 h, 64 b, 2 s); 32 q/block.
// logits MFMA (Qb/Khb global) -> reg softmax -> attLb LDS (waves 0,1 store)
// -> coalesced OFFb dword scatter (ds_add) -> Am bf16 -> AV MFMA (VTg) ->
// pair-mean + residual.  LDS 25.6 KB -> 6 blocks/CU.
// ---------------------------------------------------------------------------
__global__ __launch_bounds__(256) void scatter_av(
    const float* __restrict__ query, const float* __restrict__ refp,
    const short* __restrict__ Qb, const short* __restrict__ Khb,
    const short* __restrict__ VTg, const unsigned* __restrict__ OFFu,
    float* __restrict__ out)
{
    const int h = blockIdx.x, b = blockIdx.y, s = blockIdx.z;
    const int q0 = s * 32;
    const int t = threadIdx.x, lane = t & 63, wave = t >> 6;
    const int quad = lane >> 4, col = lane & 15;
    const int mw = wave & 1;

    __shared__ __align__(16) short attLb[32 * 136];  // 8704 B
    __shared__ __align__(16) float Am[32 * 132];     // 16896 B
    short* Amb = (short*)Am;                         // alias [32][136] bf16

    // zero Am
    {
        #pragma unroll
        for (int u = 0; u < 17; ++u) {
            const int idx = t + 256 * u;
            if (idx < 32 * 132) Am[idx] = 0.f;
        }
    }

    // logits + softmax (waves 0,1 own m-tiles; 2,3 duplicate, stores gated)
    {
        const s16x8 aq = *(const s16x8*)(Qb +
            ((size_t)b * 64 + q0 + mw * 16 + col) * 256 + h * 32 + quad * 8);
        f32x4 lacc[8];
        #pragma unroll
        for (int t8 = 0; t8 < 8; ++t8) {
            const short* src = (t8 < 4)
                ? (Qb  + ((size_t)b * 64 + 16 * t8 + col) * 256)
                : (Khb + ((size_t)b * 64 + 16 * (t8 - 4) + col) * 256);
            const s16x8 bk = *(const s16x8*)(src + h * 32 + quad * 8);
            const f32x4 z = {0.f, 0.f, 0.f, 0.f};
            lacc[t8] = __builtin_amdgcn_mfma_f32_16x16x32_bf16(aq, bk, z, 0, 0, 0);
        }
        if (wave < 2) {
            #pragma unroll
            for (int r = 0; r < 4; ++r) {
                float m = lacc[0][r];
                #pragma unroll
                for (int t8 = 1; t8 < 8; ++t8) m = fmaxf(m, lacc[t8][r]);
                #pragma unroll
                for (int sh = 1; sh < 16; sh <<= 1) m = fmaxf(m, __shfl_xor(m, sh, 64));
                float e[8], ssum = 0.f;
                #pragma unroll
                for (int t8 = 0; t8 < 8; ++t8) {
                    e[t8] = __expf(lacc[t8][r] - m); ssum += e[t8];
                }
                #pragma unroll
                for (int sh = 1; sh < 16; sh <<= 1) ssum += __shfl_xor(ssum, sh, 64);
                const float inv = 1.0f / ssum;
                const int ql = mw * 16 + 4 * quad + r;
                #pragma unroll
                for (int t8 = 0; t8 < 8; ++t8)
                    attLb[ql * 136 + 16 * t8 + col] = (short)f2bf(e[t8] * inv);
            }
        }
    }
    __syncthreads();

    // scatter: q = t>>3 (0..31), fg = t&7; f = fg + 8i (coalesced dwords)
    {
        const int q = t >> 3, fg = t & 7;
        const int qg = b * 64 + q0 + q;
        const unsigned* offrow = OFFu + (size_t)qg * 1024 + h * 128;
        const float* rp8 = refp + (size_t)qg * 8;
        float rpl[8];
        #pragma unroll
        for (int j = 0; j < 8; ++j) rpl[j] = rp8[j];
        float* rowW = &Am[q * 132];
        const short* arow = &attLb[q * 136];
        for (int i = 0; i < 16; ++i) {
            const int f = fg + 8 * i;
            const unsigned u = offrow[f];
            const float ox = __uint_as_float(u << 16);
            const float oy = __uint_as_float(u & 0xFFFF0000u);
            const float a = bf2f((unsigned short)arow[f]);
            const int l = f & 3;
            const float gx = 8.f * (rpl[l * 2 + 0] + ox * 0.125f) - 0.5f;
            const float gy = 4.f * (rpl[l * 2 + 1] + oy * 0.25f) - 0.5f;
            const float x0f = floorf(gx), y0f = floorf(gy);
            const float wx = gx - x0f, wy = gy - y0f;
            const int x0 = (int)x0f, y0 = (int)y0f;
            const int base = (f >> 5) * 32;
            const bool xv0 = (x0 >= 0) && (x0 < 8);
            const bool xv1 = (x0 >= -1) && (x0 < 7);
            const bool yv0 = (y0 >= 0) && (y0 < 4);
            const bool yv1 = (y0 >= -1) && (y0 < 3);
            if (xv0 && yv0) unsafeAtomicAdd(&rowW[base + y0 * 8 + x0],           a * (1.f - wx) * (1.f - wy));
            if (xv1 && yv0) unsafeAtomicAdd(&rowW[base + y0 * 8 + x0 + 1],       a * wx * (1.f - wy));
            if (xv0 && yv1) unsafeAtomicAdd(&rowW[base + (y0 + 1) * 8 + x0],     a * (1.f - wx) * wy);
            if (xv1 && yv1) unsafeAtomicAdd(&rowW[base + (y0 + 1) * 8 + x0 + 1], a * wx * wy);
        }
    }
    __syncthreads();

    // Am -> bf16
    {
        const int cq = t >> 3, cc = (t & 7) * 16;
        float vreg[16];
        #pragma unroll
        for (int u = 0; u < 4; ++u) {
            const float4 v = *(const float4*)&Am[cq * 132 + cc + 4 * u];
            vreg[4 * u + 0] = v.x; vreg[4 * u + 1] = v.y;
            vreg[4 * u + 2] = v.z; vreg[4 * u + 3] = v.w;
        }
        __syncthreads();
        #pragma unroll
        for (int u = 0; u < 2; ++u) {
            s16x8 o;
            #pragma unroll
            for (int j = 0; j < 8; ++j) o[j] = (short)f2bf(vreg[u * 8 + j]);
            *(s16x8*)&Amb[cq * 136 + cc + u * 8] = o;
        }
    }
    __syncthreads();

    // AV: wave -> (m-tile mw, n-tile nt); pair-mean + residual
    {
        const int nt = wave >> 1;
        f32x4 oacc = {};
        #pragma unroll
        for (int ks = 0; ks < 4; ++ks) {
            const s16x8 af = *(const s16x8*)&Amb[(mw * 16 + col) * 136
                                                 + ks * 32 + quad * 8];
            const s16x8 bv = *(const s16x8*)(VTg +
                ((size_t)(b * 8 + h) * 32 + nt * 16 + col) * 128
                + ks * 32 + quad * 8);
            oacc = __builtin_amdgcn_mfma_f32_16x16x32_bf16(af, bv, oacc, 0, 0, 0);
        }
        const int d = h * 32 + nt * 16 + col;
        #pragma unroll
        for (int pr = 0; pr < 2; ++pr) {
            const float avg = 0.5f * (oacc[2 * pr] + oacc[2 * pr + 1]);
            const int pj = (q0 >> 1) + mw * 8 + quad * 2 + pr;
            const size_t re = ((size_t)b * 64 + pj) * 256 + d;
            const size_t ro = ((size_t)b * 64 + pj + 32) * 256 + d;
            out[re] = query[re] + avg;
            out[ro] = query[ro] + avg;
        }
    }
}

extern "C" void kernel_launch(void* const* d_in, const int* in_sizes, int n_in,
                              void* d_out, int out_size, void* d_ws, size_t ws_size,
                              hipStream_t stream) {
    (void)in_sizes; (void)n_in; (void)out_size; (void)ws_size;
    const float* query      = (const float*)d_in[0];
    const float* key_hist   = (const float*)d_in[1];
    const float* value_hist = (const float*)d_in[2];
    const float* refp       = (const float*)d_in[3];
    const float* W_off      = (const float*)d_in[5];
    const float* b_off      = (const float*)d_in[6];

    char* ws = (char*)d_ws;
    short* Qb   = (short*)(ws);                    // 2 MB
    short* Khb  = (short*)(ws + (2u << 20));       // 2 MB
    short* Wtb  = (short*)(ws + (4u << 20));       // 1 MB
    short* VTg  = (short*)(ws + (5u << 20));       // 4 MB
    short* OFFb = (short*)(ws + (9u << 20));       // 16.78 MB
    float* out  = (float*)d_out;

    prep<<<3072, 256, 0, stream>>>(W_off, query, key_hist, value_hist,
                                   Wtb, Qb, Khb, VTg);
    gemm_k<<<dim3(16, 32), 256, 0, stream>>>(Qb, Wtb, b_off, OFFb);
    scatter_av<<<dim3(8, 64, 2), 256, 0, stream>>>(query, refp, Qb, Khb, VTg,
                                                   (const unsigned*)OFFb, out);
}